// Round 1
// baseline (325.713 us; speedup 1.0000x reference)
//
#include <hip/hip_runtime.h>

#define N_ROWS 4096
#define IN_F   4096
#define OUT_F  4096
#define C_CB   256
#define KDIM   4096   // C_CB * 16

typedef short bf16x8 __attribute__((ext_vector_type(8)));
typedef float f32x4  __attribute__((ext_vector_type(4)));

union ABFrag { unsigned long long u[2]; bf16x8 v; };

__device__ __forceinline__ unsigned int f2bf(float f) {
    unsigned int u = __builtin_bit_cast(unsigned int, f);
    return (u + 0x7FFFu + ((u >> 16) & 1u)) >> 16;   // RNE
}

// ---------------- Kernel 1: decision-tree descent -> idx8[n][c] ----------------
__global__ void k_idx(const float* __restrict__ input, const int* __restrict__ dims,
                      const float* __restrict__ thr, unsigned char* __restrict__ idx8) {
    const int n = blockIdx.x;
    const int c = threadIdx.x;
    const float* row = input + (size_t)n * IN_F;
    int4 d = *(const int4*)(dims + c * 4);
    const float* th = thr + c * 15;
    float x0 = row[d.x], x1 = row[d.y], x2 = row[d.z], x3 = row[d.w];
    int b0 = x0 > th[0];
    int j1 = 1 + b0;
    int b1 = x1 > th[j1];
    int j2 = 2 * j1 + 1 + b1;
    int b2 = x2 > th[j2];
    int j3 = 2 * j2 + 1 + b2;
    int b3 = x3 > th[j3];
    idx8[n * C_CB + c] = (unsigned char)((b0 << 3) | (b1 << 2) | (b2 << 1) | b3);
}

// ---------------- Kernel 2: lut fp32 -> bf16 (same [out][kdim] layout) ----------------
__global__ void k_cvt(const float* __restrict__ lut, unsigned short* __restrict__ lutb) {
    const int i = (blockIdx.x * blockDim.x + threadIdx.x) * 8;
    float4 a = *(const float4*)(lut + i);
    float4 b = *(const float4*)(lut + i + 4);
    uint4 o;
    o.x = f2bf(a.x) | (f2bf(a.y) << 16);
    o.y = f2bf(a.z) | (f2bf(a.w) << 16);
    o.z = f2bf(b.x) | (f2bf(b.y) << 16);
    o.w = f2bf(b.z) | (f2bf(b.w) << 16);
    *(uint4*)(lutb + i) = o;
}

// ---------------- Kernel 3: GEMM with implicit one-hot A ----------------
// out[n][k] = sum_c lut[k][c][idx[n][c]]
// A (M=4096 x K=4096) one-hot from idx, built in registers.
// B (K x N=4096) = lutb[out][kdim] (i.e. B^T rows), staged to LDS.
#define BM 128
#define BN 128
#define BKT 64          // kdim per LDS stage (2 MFMA K-steps of 32)
#define IDXP 272        // idx LDS row pitch (256 + 16: breaks bank conflicts)

template<bool STAGE_FP32>
__global__ __launch_bounds__(256, 2) void k_gemm(const unsigned short* __restrict__ lutb,
                                                 const float* __restrict__ lutf,
                                                 const unsigned char* __restrict__ idx8,
                                                 float* __restrict__ out) {
    __shared__ unsigned char smem[128 * IDXP + BN * BKT * 2];   // 34816 + 16384 = 50 KB
    unsigned char* ish = smem;
    unsigned char* bsh = smem + 128 * IDXP;

    const int t   = threadIdx.x;
    const int l15 = t & 15;
    const int q   = (t >> 4) & 3;          // quad within wave
    const int w   = t >> 6;
    const int wm  = w >> 1, wn = w & 1;    // 2x2 waves -> 64x64 tile each
    const int m0  = blockIdx.y * BM;
    const int n0  = blockIdx.x * BN;

    // --- idx prologue: stage idx8 rows [m0..m0+127][0..255] into LDS (padded pitch) ---
    {
        int r = t >> 1, h = t & 1;
        const uint4* src = (const uint4*)(idx8 + (size_t)(m0 + r) * C_CB + h * 128);
        uint4* dst = (uint4*)(ish + r * IDXP + h * 128);
        #pragma unroll
        for (int i = 0; i < 8; i++) dst[i] = src[i];
    }

    f32x4 acc[4][4];
    #pragma unroll
    for (int mi = 0; mi < 4; mi++)
        #pragma unroll
        for (int ni = 0; ni < 4; ni++)
            acc[mi][ni] = (f32x4){0.f, 0.f, 0.f, 0.f};

    const int xorv = l15 & 7;                       // B-row swizzle key (row&7)
    const int bRowByte = (wn * 64 + l15) * (BKT * 2);
    const int aRowBase = (wm * 64 + l15) * IDXP;

    for (int kb = 0; kb < KDIM; kb += BKT) {
        // --- stage B tile: [128 out-rows][64 kdim] bf16, chunk-XOR swizzled ---
        if (!STAGE_FP32) {
            #pragma unroll
            for (int qq = 0; qq < 4; qq++) {
                int L = qq * 256 + t;               // 16B chunk index in LDS
                int r = L >> 3, p = L & 7;
                int c = p ^ (r & 7);                // global chunk stored at position p
                const unsigned short* g = lutb + (size_t)(n0 + r) * KDIM + kb + c * 8;
                __builtin_amdgcn_global_load_lds(
                    (const __attribute__((address_space(1))) void*)g,
                    (__attribute__((address_space(3))) void*)(bsh + L * 16), 16, 0, 0);
            }
        } else {
            #pragma unroll
            for (int qq = 0; qq < 4; qq++) {
                int L = qq * 256 + t;
                int r = L >> 3, p = L & 7;
                int c = p ^ (r & 7);
                const float* g = lutf + (size_t)(n0 + r) * KDIM + kb + c * 8;
                float4 f0 = *(const float4*)g;
                float4 f1 = *(const float4*)(g + 4);
                uint4 o;
                o.x = f2bf(f0.x) | (f2bf(f0.y) << 16);
                o.y = f2bf(f0.z) | (f2bf(f0.w) << 16);
                o.z = f2bf(f1.x) | (f2bf(f1.y) << 16);
                o.w = f2bf(f1.z) | (f2bf(f1.w) << 16);
                *(uint4*)(bsh + L * 16) = o;
            }
        }
        __syncthreads();

        #pragma unroll
        for (int s = 0; s < 2; s++) {
            const int c0 = (kb >> 4) + 2 * s;       // codebook pair (c0, c0+1)

            // B fragments: B[kdim=quad*8+j][n=l15] via ds_read_b128 (swizzled chunk)
            ABFrag bf[4];
            const int chunkOff = ((s * 4 + q) ^ xorv) * 16;
            #pragma unroll
            for (int ni = 0; ni < 4; ni++)
                bf[ni].v = *(const bf16x8*)(bsh + bRowByte + ni * (16 * BKT * 2) + chunkOff);

            // A fragments: one-hot from idx, A[m=l15][k=quad*8+j]
            ABFrag af[4];
            #pragma unroll
            for (int mi = 0; mi < 4; mi++) {
                unsigned int v = *(const unsigned short*)(ish + aRowBase + mi * 16 * IDXP + c0);
                unsigned int idx0 = v & 0xFFu, idx1 = v >> 8;
                unsigned int T = (q >> 1) ? idx1 : idx0;        // quads 0,1 -> cb c0; 2,3 -> c0+1
                unsigned int rel = T - ((q & 1) << 3);          // position within 8-wide window
                unsigned long long sh = 0x3F80ull << ((rel & 3) << 4);  // bf16 1.0
                af[mi].u[0] = (rel < 4u) ? sh : 0ull;
                af[mi].u[1] = ((rel - 4u) < 4u) ? sh : 0ull;    // rel in [4,8); wraps safe
            }

            #pragma unroll
            for (int mi = 0; mi < 4; mi++)
                #pragma unroll
                for (int ni = 0; ni < 4; ni++)
                    acc[mi][ni] = __builtin_amdgcn_mfma_f32_16x16x32_bf16(
                        af[mi].v, bf[ni].v, acc[mi][ni], 0, 0, 0);
        }
        __syncthreads();
    }

    // --- epilogue: D row = quad*4 + reg, col = l15 ---
    #pragma unroll
    for (int mi = 0; mi < 4; mi++) {
        #pragma unroll
        for (int ni = 0; ni < 4; ni++) {
            const int row0 = m0 + wm * 64 + mi * 16 + q * 4;
            const int col  = n0 + wn * 64 + ni * 16 + l15;
            #pragma unroll
            for (int r = 0; r < 4; r++)
                out[(size_t)(row0 + r) * OUT_F + col] = acc[mi][ni][r];
        }
    }
}

extern "C" void kernel_launch(void* const* d_in, const int* in_sizes, int n_in,
                              void* d_out, int out_size, void* d_ws, size_t ws_size,
                              hipStream_t stream) {
    const float* input = (const float*)d_in[0];
    const int*   dims  = (const int*)d_in[1];
    // d_in[2] selection_matrix, d_in[4] tree_des_mat: structure folded into the kernel
    const float* thr   = (const float*)d_in[3];
    const float* lut   = (const float*)d_in[5];
    float* out = (float*)d_out;

    const size_t lutbBytes = (size_t)OUT_F * KDIM * 2;   // 32 MB
    const size_t idxBytes  = (size_t)N_ROWS * C_CB;      // 1 MB

    dim3 gg(OUT_F / BN, N_ROWS / BM);

    if (ws_size >= lutbBytes + idxBytes) {
        unsigned short* lutb = (unsigned short*)d_ws;
        unsigned char*  idx8 = (unsigned char*)d_ws + lutbBytes;
        k_idx<<<N_ROWS, C_CB, 0, stream>>>(input, dims, thr, idx8);
        k_cvt<<<(OUT_F * KDIM) / (256 * 8), 256, 0, stream>>>(lut, lutb);
        k_gemm<false><<<gg, 256, 0, stream>>>(lutb, lut, idx8, out);
    } else {
        unsigned char* idx8 = (unsigned char*)d_ws;
        k_idx<<<N_ROWS, C_CB, 0, stream>>>(input, dims, thr, idx8);
        k_gemm<true><<<gg, 256, 0, stream>>>(nullptr, lut, idx8, out);
    }
}

// Round 2
// 314.532 us; speedup vs baseline: 1.0355x; 1.0355x over previous
//
#include <hip/hip_runtime.h>

#define N_ROWS 4096
#define IN_F   4096
#define OUT_F  4096
#define C_CB   256
#define KDIM   4096   // C_CB * 16

typedef short bf16x8 __attribute__((ext_vector_type(8)));
typedef float f32x4  __attribute__((ext_vector_type(4)));

union ABFrag { unsigned long long u[2]; bf16x8 v; };

__device__ __forceinline__ unsigned int f2bf(float f) {
    unsigned int u = __builtin_bit_cast(unsigned int, f);
    return (u + 0x7FFFu + ((u >> 16) & 1u)) >> 16;   // RNE
}

// ---------------- Kernel 1: tree descent -> packed nibbles idx4[cbp][n] ----------------
// idx4[(c>>1)*N_ROWS + n] = idx(c even) | idx(c odd)<<4
__global__ void k_idx(const float* __restrict__ input, const int* __restrict__ dims,
                      const float* __restrict__ thr, unsigned char* __restrict__ idx4) {
    const int n = blockIdx.x;
    const int c = threadIdx.x;
    const float* row = input + (size_t)n * IN_F;
    int4 d = *(const int4*)(dims + c * 4);
    const float* th = thr + c * 15;
    float x0 = row[d.x], x1 = row[d.y], x2 = row[d.z], x3 = row[d.w];
    int b0 = x0 > th[0];
    int j1 = 1 + b0;
    int b1 = x1 > th[j1];
    int j2 = 2 * j1 + 1 + b1;
    int b2 = x2 > th[j2];
    int j3 = 2 * j2 + 1 + b2;
    int b3 = x3 > th[j3];
    int idx = (b0 << 3) | (b1 << 2) | (b2 << 1) | b3;
    int other = __shfl_xor(idx, 1);
    if (!(c & 1))
        idx4[(c >> 1) * N_ROWS + n] = (unsigned char)(idx | (other << 4));
}

// ---------------- Kernel 2: lut fp32 -> bf16 (same [out][kdim] layout) ----------------
__global__ void k_cvt(const float* __restrict__ lut, unsigned short* __restrict__ lutb) {
    const int i = (blockIdx.x * blockDim.x + threadIdx.x) * 8;
    float4 a = *(const float4*)(lut + i);
    float4 b = *(const float4*)(lut + i + 4);
    uint4 o;
    o.x = f2bf(a.x) | (f2bf(a.y) << 16);
    o.y = f2bf(a.z) | (f2bf(a.w) << 16);
    o.z = f2bf(b.x) | (f2bf(b.y) << 16);
    o.w = f2bf(b.z) | (f2bf(b.w) << 16);
    *(uint4*)(lutb + i) = o;
}

// ---------------- Kernel 3: GEMM with implicit one-hot A ----------------
// out[n][k] = sum_c lut[k][c][idx[n][c]]
// Row-permuted tiles: within tile mi, MFMA row m maps to global row wm*64 + 4*m + mi,
// so one ds_read_b32 of idx nibbles serves all 4 mi fragments.
#define BM 128
#define BN 128
#define BKT 64          // kdim per LDS stage (2 MFMA K-steps of 32)

template<bool STAGE_FP32>
__global__ __launch_bounds__(256, 4) void k_gemm(const unsigned short* __restrict__ lutb,
                                                 const float* __restrict__ lutf,
                                                 const unsigned char* __restrict__ idx4,
                                                 float* __restrict__ out) {
    __shared__ unsigned char smem[16384 + BN * BKT * 2];   // idx 16KB + B 16KB = 32 KB
    unsigned char* ish = smem;                              // [cbp 128][row 128]
    unsigned char* bsh = smem + 16384;

    const int t   = threadIdx.x;
    const int l15 = t & 15;
    const int q   = (t >> 4) & 3;          // quad within wave
    const int w   = t >> 6;
    const int wm  = w >> 1, wn = w & 1;    // 2x2 waves -> 64x64 tile each
    const int m0  = blockIdx.y * BM;
    const int n0  = blockIdx.x * BN;

    // --- idx prologue: stage packed nibbles [cbp 0..127][rows m0..m0+127] -> LDS ---
    #pragma unroll
    for (int qq = 0; qq < 4; qq++) {
        int L = qq * 256 + t;              // 16B chunk: cbp = L>>3, row-part = L&7
        const unsigned char* g = idx4 + (size_t)(L >> 3) * N_ROWS + m0 + (L & 7) * 16;
        __builtin_amdgcn_global_load_lds(
            (const __attribute__((address_space(1))) void*)g,
            (__attribute__((address_space(3))) void*)(ish + L * 16), 16, 0, 0);
    }

    f32x4 acc[4][4];
    #pragma unroll
    for (int mi = 0; mi < 4; mi++)
        #pragma unroll
        for (int ni = 0; ni < 4; ni++)
            acc[mi][ni] = (f32x4){0.f, 0.f, 0.f, 0.f};

    const int xorv = l15 & 7;                       // B chunk swizzle key
    const int bRowByte = (wn * 64 + l15) * (BKT * 2);
    const int aByte = wm * 64 + l15 * 4;            // idx word offset within a cbp row
    const int qh4  = (q >> 1) * 4;                  // nibble select: cb c0 vs c0+1
    const unsigned int sub8 = (q & 1) << 3;         // window offset within codebook

    for (int kb = 0; kb < KDIM; kb += BKT) {
        // --- stage B tile: [128 out-rows][64 kdim] bf16, chunk-XOR swizzled ---
        if (!STAGE_FP32) {
            #pragma unroll
            for (int qq = 0; qq < 4; qq++) {
                int L = qq * 256 + t;               // 16B chunk index in LDS
                int r = L >> 3, p = L & 7;
                int c = p ^ (r & 7);                // global chunk stored at position p
                const unsigned short* g = lutb + (size_t)(n0 + r) * KDIM + kb + c * 8;
                __builtin_amdgcn_global_load_lds(
                    (const __attribute__((address_space(1))) void*)g,
                    (__attribute__((address_space(3))) void*)(bsh + L * 16), 16, 0, 0);
            }
        } else {
            #pragma unroll
            for (int qq = 0; qq < 4; qq++) {
                int L = qq * 256 + t;
                int r = L >> 3, p = L & 7;
                int c = p ^ (r & 7);
                const float* g = lutf + (size_t)(n0 + r) * KDIM + kb + c * 8;
                float4 f0 = *(const float4*)g;
                float4 f1 = *(const float4*)(g + 4);
                uint4 o;
                o.x = f2bf(f0.x) | (f2bf(f0.y) << 16);
                o.y = f2bf(f0.z) | (f2bf(f0.w) << 16);
                o.z = f2bf(f1.x) | (f2bf(f1.y) << 16);
                o.w = f2bf(f1.z) | (f2bf(f1.w) << 16);
                *(uint4*)(bsh + L * 16) = o;
            }
        }
        __syncthreads();

        #pragma unroll
        for (int s = 0; s < 2; s++) {
            const int cbp = (kb >> 5) + s;          // packed codebook pair index

            // B fragments: B[kdim=quad*8+j][n] via ds_read_b128 (swizzled chunk)
            ABFrag bf[4];
            const int chunkOff = ((s * 4 + q) ^ xorv) * 16;
            #pragma unroll
            for (int ni = 0; ni < 4; ni++)
                bf[ni].v = *(const bf16x8*)(bsh + bRowByte + ni * (16 * BKT * 2) + chunkOff);

            // idx word: 4 bytes = rows 4*l15..4*l15+3 (tiles mi=0..3), both codebooks
            const unsigned int w32 = *(const unsigned int*)(ish + cbp * 128 + aByte);

            // A fragments: one-hot, A[m=l15][k=quad*8+j]
            ABFrag af[4];
            #pragma unroll
            for (int mi = 0; mi < 4; mi++) {
                unsigned int T = (w32 >> (mi * 8 + qh4)) & 0xFu;
                unsigned int rel = T - sub8;                    // one-hot iff rel in [0,8)
                unsigned long long sh = 0x3F80ull << ((rel & 3) << 4);  // bf16 1.0
                af[mi].u[0] = (rel < 4u) ? sh : 0ull;
                af[mi].u[1] = ((rel - 4u) < 4u) ? sh : 0ull;
            }

            #pragma unroll
            for (int mi = 0; mi < 4; mi++)
                #pragma unroll
                for (int ni = 0; ni < 4; ni++)
                    acc[mi][ni] = __builtin_amdgcn_mfma_f32_16x16x32_bf16(
                        af[mi].v, bf[ni].v, acc[mi][ni], 0, 0, 0);
        }
        __syncthreads();
    }

    // --- epilogue: MFMA row m = q*4 + r -> global row = m0 + wm*64 + 4*m + mi ---
    #pragma unroll
    for (int mi = 0; mi < 4; mi++) {
        #pragma unroll
        for (int ni = 0; ni < 4; ni++) {
            const int col = n0 + wn * 64 + ni * 16 + l15;
            #pragma unroll
            for (int r = 0; r < 4; r++) {
                const int row = m0 + wm * 64 + 4 * (q * 4 + r) + mi;
                out[(size_t)row * OUT_F + col] = acc[mi][ni][r];
            }
        }
    }
}

extern "C" void kernel_launch(void* const* d_in, const int* in_sizes, int n_in,
                              void* d_out, int out_size, void* d_ws, size_t ws_size,
                              hipStream_t stream) {
    const float* input = (const float*)d_in[0];
    const int*   dims  = (const int*)d_in[1];
    // d_in[2] selection_matrix, d_in[4] tree_des_mat: structure folded into the kernels
    const float* thr   = (const float*)d_in[3];
    const float* lut   = (const float*)d_in[5];
    float* out = (float*)d_out;

    const size_t lutbBytes = (size_t)OUT_F * KDIM * 2;       // 32 MB
    const size_t idxBytes  = (size_t)(C_CB / 2) * N_ROWS;    // 512 KB

    dim3 gg(OUT_F / BN, N_ROWS / BM);

    if (ws_size >= lutbBytes + idxBytes) {
        unsigned short* lutb = (unsigned short*)d_ws;
        unsigned char*  idx4 = (unsigned char*)d_ws + lutbBytes;
        k_idx<<<N_ROWS, C_CB, 0, stream>>>(input, dims, thr, idx4);
        k_cvt<<<(OUT_F * KDIM) / (256 * 8), 256, 0, stream>>>(lut, lutb);
        k_gemm<false><<<gg, 256, 0, stream>>>(lutb, lut, idx4, out);
    } else {
        unsigned char* idx4 = (unsigned char*)d_ws;
        k_idx<<<N_ROWS, C_CB, 0, stream>>>(input, dims, thr, idx4);
        k_gemm<true><<<gg, 256, 0, stream>>>(nullptr, lut, idx4, out);
    }
}